// Round 4
// baseline (357.102 us; speedup 1.0000x reference)
//
#include <hip/hip_runtime.h>

// MHA: B=4, H=16, S=2048, D_MODEL=1024, DK=64. fp32 in/out, bf16 MFMA compute.
// R11: 8-phase 256x256 QKV GEMM (T3+T4+T5). R10 post-mortem: dbuf behind a
// draining __syncthreads cost occupancy for nothing (111us, MfmaUtil 18%).
// New gemm8_qkv: BM=BN=256 BK=64, 8 waves (512 thr), 128KB LDS dbuf.
// Per K-tile 4 phases (quadrant walk mq0nh0,mq0nh1,mq1nh1,mq1nh0); per phase:
// {ds_read frags, stage ONE 16KB piece (2 gload_lds/thread), 16 MFMA w/
// setprio, s_waitcnt lgkmcnt(0) vmcnt(6), s_barrier}. Counted vmcnt keeps 3
// stage-pieces in flight across barriers (never drains). A stored per-mq
// [mq][wm*64+r][64], B per-nh [nh][wn*32+r][64] so each piece is dead >=1
// phase before restage and every stage has >=4-phase landing margin at
// vmcnt(6). Stage schedule (iter computes tiles T,T+1):
//   P0:(T+1).Bnh0 P1:(T+1).Amq1 P2:(T+2).Amq0 P3:(T+2).Bnh1
//   P4:(T+2).Bnh0 P5:(T+2).Amq1 P6:(T+3).Amq0 P7:(T+3).Bnh1
// gemm_out reverted to R9 single-buffer 128^2 (4 blocks/CU). Attn/cvt as R9.

typedef __attribute__((ext_vector_type(8))) __bf16 bf16x8;
typedef __attribute__((ext_vector_type(4))) __bf16 bf16x4;
typedef __attribute__((ext_vector_type(4))) float f32x4;
typedef __attribute__((ext_vector_type(4))) unsigned int u32x4;

#define SCALE_FOLD 0.18033688011112043f  // log2(e) / sqrt(64), folded into Q

__device__ __forceinline__ void async_copy16(const void* g, void* lds) {
  __builtin_amdgcn_global_load_lds(
      (const __attribute__((address_space(1))) void*)g,
      (__attribute__((address_space(3))) void*)lds, 16, 0, 0);
}

// Stage a [ROWS x 64 bf16] tile (row pitch `ld` elems) into LDS, 16B/lane,
// XOR chunk swizzle: LDS slot (row, c) holds global chunk c ^ (row & 7).
template <int ROWS, int THREADS>
__device__ __forceinline__ void stage_tile(const __bf16* __restrict__ g, int ld,
                                           __bf16* lds, int tid) {
  const int wave_base = tid & ~63;
#pragma unroll
  for (int r = 0; r < ROWS * 8 / THREADS; ++r) {
    int slot = r * THREADS + tid;
    int row = slot >> 3;
    int c = slot & 7;
    int gc = c ^ (row & 7);
    async_copy16(g + row * ld + gc * 8, lds + (r * THREADS + wave_base) * 8);
  }
}

// Stage one permuted 128-row x 64-col piece (16 KB) with 512 threads.
// Local lds row rho maps to global row ((rho>>SH)<<(SH+1)) + off + (rho&mask).
template <int SH>
__device__ __forceinline__ void stage_piece(const __bf16* __restrict__ g,
                                            int ld, int off, __bf16* lds,
                                            int tid) {
  const int wave_base = tid & ~63;
#pragma unroll
  for (int rnd = 0; rnd < 2; ++rnd) {
    int slot = rnd * 512 + tid;
    int rho = slot >> 3;
    int c = slot & 7;
    int gc = c ^ (rho & 7);
    int grow = ((rho >> SH) << (SH + 1)) + off + (rho & ((1 << SH) - 1));
    async_copy16(g + (size_t)grow * ld + gc * 8,
                 lds + (rnd * 512 + wave_base) * 8);
  }
}

// Read one 8-elem (16B) fragment chunk from a width-64 XOR-swizzled tile.
__device__ __forceinline__ bf16x8 frag_ld(const __bf16* lds, int row, int chunk) {
  return *(const bf16x8*)(lds + row * 64 + ((chunk ^ (row & 7)) << 3));
}

// Pack two fp32 into one u32 of 2 bf16 (lo, hi). Compiler fuses the casts.
__device__ __forceinline__ unsigned pk_bf16(float lo, float hi) {
  unsigned short l = __builtin_bit_cast(unsigned short, (__bf16)lo);
  unsigned short h = __builtin_bit_cast(unsigned short, (__bf16)hi);
  return (unsigned)l | ((unsigned)h << 16);
}

// All 7 fp32->bf16 conversions in one dispatch; blockIdx.y selects tensor.
__global__ void cvt_all(const float* __restrict__ s0, const float* __restrict__ s1,
                        const float* __restrict__ s2, const float* __restrict__ s3,
                        const float* __restrict__ s4, const float* __restrict__ s5,
                        const float* __restrict__ s6, __bf16* d0, __bf16* d1,
                        __bf16* d2, __bf16* d3, __bf16* d4, __bf16* d5,
                        __bf16* d6, int n4_big, int n4_small) {
  const int z = blockIdx.y;
  const float* src;
  __bf16* dst;
  int n4;
  switch (z) {
    case 0: src = s0; dst = d0; n4 = n4_big; break;
    case 1: src = s1; dst = d1; n4 = n4_big; break;
    case 2: src = s2; dst = d2; n4 = n4_big; break;
    case 3: src = s3; dst = d3; n4 = n4_small; break;
    case 4: src = s4; dst = d4; n4 = n4_small; break;
    case 5: src = s5; dst = d5; n4 = n4_small; break;
    default: src = s6; dst = d6; n4 = n4_small; break;
  }
  int i = blockIdx.x * blockDim.x + threadIdx.x;
  if (i < n4) {
    float4 v = ((const float4*)src)[i];
    bf16x4 o = {(__bf16)v.x, (__bf16)v.y, (__bf16)v.z, (__bf16)v.w};
    ((bf16x4*)dst)[i] = o;
  }
}

// ---------------- 8-phase 256x256 QKV GEMM ----------------
// C[m,n] = sum_k A[m,k]*B[n,k] (+bias). 8 waves 2Mx4N, per-wave 128x64 out.
__global__ __launch_bounds__(512, 2) void gemm8_qkv(
    const __bf16* __restrict__ xq, const __bf16* __restrict__ xk,
    const __bf16* __restrict__ xv, const __bf16* __restrict__ wq,
    const __bf16* __restrict__ wk, const __bf16* __restrict__ wv,
    const float* __restrict__ bq, const float* __restrict__ bk,
    const float* __restrict__ bv, __bf16* Qb, __bf16* Kb, __bf16* Vtb) {
  __shared__ alignas(16) __bf16 Ab[2][256 * 64];  // [buf][mq*8192 + rho*64 + k]
  __shared__ alignas(16) __bf16 Bb[2][256 * 64];  // [buf][nh*8192 + rho*64 + k]

  const int tid = threadIdx.x;
  const int lane = tid & 63;
  const int w = tid >> 6;          // 0..7
  const int wm = w >> 2, wn = w & 3;
  const int l15 = lane & 15, quad = lane >> 4;
  const int K = 1024, NT = 16;

  const int bid = blockIdx.x;  // 0..127
  const int z = blockIdx.y;
  const int xcd = bid & 7, j = bid >> 3;  // j 0..15

  const __bf16 *A, *B;
  const float* bias;
  __bf16* outp;
  int mblk, nblk;
  if (z == 0) {
    A = xq; B = wq; bias = bq; outp = Qb;
    mblk = xcd * 4 + (j >> 2); nblk = j & 3;
  } else if (z == 1) {
    A = xk; B = wk; bias = bk; outp = Kb;
    mblk = xcd * 4 + (j >> 2); nblk = j & 3;
  } else {  // V operand-swapped: A = Wv (M=1024), B = xv (N=8192) -> V^T out
    A = wv; B = xv; bias = bv; outp = Vtb;
    mblk = j & 3; nblk = xcd * 4 + (j >> 2);
  }
  const int m0 = mblk * 256, n0 = nblk * 256;
  const __bf16* Ag = A + (size_t)m0 * K;
  const __bf16* Bg = B + (size_t)n0 * K;

  f32x4 acc[8][4] = {};  // [mi_g][nj_g]

  // Prologue: tile0 {Amq0, Bnh1, Bnh0, Amq1}, tile1 {Amq0, Bnh1}.
  stage_piece<6>(Ag, K, 0, Ab[0], tid);                    // t0.Amq0
  stage_piece<5>(Bg, K, 32, Bb[0] + 8192, tid);            // t0.Bnh1
  stage_piece<5>(Bg, K, 0, Bb[0], tid);                    // t0.Bnh0
  stage_piece<6>(Ag, K, 64, Ab[0] + 8192, tid);            // t0.Amq1
  stage_piece<6>(Ag + 64, K, 0, Ab[1], tid);               // t1.Amq0
  stage_piece<5>(Bg + 64, K, 32, Bb[1] + 8192, tid);       // t1.Bnh1
  asm volatile("s_waitcnt vmcnt(4)" ::: "memory");         // t0 landed
  __builtin_amdgcn_s_barrier();

  bf16x8 af[4][2];  // A frags, persist across the 2 phases of an mq

  for (int T = 0; T < NT; T += 2) {
#pragma unroll
    for (int pp = 0; pp < 8; ++pp) {
      const int ph = pp & 3;
      const int buf = pp >> 2;                 // tile T -> buf0, T+1 -> buf1
      const int mq = ph >> 1;                  // 0,0,1,1
      const int nh = (ph == 1 || ph == 2);     // 0,1,1,0

      if (ph == 0 || ph == 2) {
#pragma unroll
        for (int mi = 0; mi < 4; ++mi)
#pragma unroll
          for (int kc = 0; kc < 2; ++kc)
            af[mi][kc] = frag_ld(Ab[buf] + mq * 8192,
                                 wm * 64 + mi * 16 + l15, kc * 4 + quad);
      }
      bf16x8 bfr[2][2];
#pragma unroll
      for (int ni = 0; ni < 2; ++ni)
#pragma unroll
        for (int kc = 0; kc < 2; ++kc)
          bfr[ni][kc] = frag_ld(Bb[buf] + nh * 8192,
                                wn * 32 + ni * 16 + l15, kc * 4 + quad);

      // Stage schedule (one 16KB piece per phase, 2 gload_lds/thread).
      if (pp == 0) {
        stage_piece<5>(Bg + (size_t)(T + 1) * 64, K, 0, Bb[1], tid);
      } else if (pp == 1) {
        stage_piece<6>(Ag + (size_t)(T + 1) * 64, K, 64, Ab[1] + 8192, tid);
      } else if (pp == 2) {
        if (T + 2 < NT)
          stage_piece<6>(Ag + (size_t)(T + 2) * 64, K, 0, Ab[0], tid);
      } else if (pp == 3) {
        if (T + 2 < NT)
          stage_piece<5>(Bg + (size_t)(T + 2) * 64, K, 32, Bb[0] + 8192, tid);
      } else if (pp == 4) {
        if (T + 2 < NT)
          stage_piece<5>(Bg + (size_t)(T + 2) * 64, K, 0, Bb[0], tid);
      } else if (pp == 5) {
        if (T + 2 < NT)
          stage_piece<6>(Ag + (size_t)(T + 2) * 64, K, 64, Ab[0] + 8192, tid);
      } else if (pp == 6) {
        if (T + 3 < NT)
          stage_piece<6>(Ag + (size_t)(T + 3) * 64, K, 0, Ab[1], tid);
      } else {
        if (T + 3 < NT)
          stage_piece<5>(Bg + (size_t)(T + 3) * 64, K, 32, Bb[1] + 8192, tid);
      }

      __builtin_amdgcn_s_setprio(1);
#pragma unroll
      for (int kc = 0; kc < 2; ++kc)
#pragma unroll
        for (int mi = 0; mi < 4; ++mi)
#pragma unroll
          for (int ni = 0; ni < 2; ++ni)
            acc[mq * 4 + mi][nh * 2 + ni] =
                __builtin_amdgcn_mfma_f32_16x16x32_bf16(
                    af[mi][kc], bfr[ni][kc], acc[mq * 4 + mi][nh * 2 + ni], 0,
                    0, 0);
      __builtin_amdgcn_s_setprio(0);
      // Counted waits: all this-wave ds_reads done (so next phase may restage
      // a dead region), and >=4-phase-old stages landed. Never drains vmem.
      asm volatile("s_waitcnt lgkmcnt(0) vmcnt(6)" ::: "memory");
      __builtin_amdgcn_s_barrier();
    }
  }

#pragma unroll
  for (int mi = 0; mi < 8; ++mi) {
#pragma unroll
    for (int ii = 0; ii < 4; ++ii) {
      int grow = m0 + wm * 128 + mi * 16 + quad * 4 + ii;
#pragma unroll
      for (int nj = 0; nj < 4; ++nj) {
        int gcol = n0 + wn * 64 + nj * 16 + l15;
        float v = acc[mi][nj][ii];
        if (z == 2) {  // V^T out [B,H,64,S]
          v += bias[grow];
          int h = grow >> 6, dd = grow & 63;
          int b = gcol >> 11, s = gcol & 2047;
          outp[(((b * 16 + h) * 64 + dd) * 2048) + s] = (__bf16)v;
        } else {  // Q/K out [B,H,S,64]
          v += bias[gcol];
          if (z == 0) v *= SCALE_FOLD;
          int h = gcol >> 6, dd = gcol & 63;
          int b = grow >> 11, s = grow & 2047;
          outp[(((b * 16 + h) * 2048 + s) * 64) + dd] = (__bf16)v;
        }
      }
    }
  }
}

// ---------------- R9 single-buffer 128x128 GEMM (gemm_out) ----------------
__device__ __forceinline__ void gemm_body(const __bf16* __restrict__ A,
                                          const __bf16* __restrict__ B,
                                          const float* __restrict__ bias,
                                          float* __restrict__ out, int K,
                                          int m0, int n0, __bf16* Alds,
                                          __bf16* Blds) {
  const int tid = threadIdx.x;
  const int lane = tid & 63;
  const int w = tid >> 6;
  const int wm = w >> 1, wn = w & 1;
  const int l15 = lane & 15, quad = lane >> 4;

  f32x4 acc[4][4] = {};

  for (int k0 = 0; k0 < K; k0 += 64) {
    stage_tile<128, 256>(A + m0 * K + k0, K, Alds, tid);
    stage_tile<128, 256>(B + n0 * K + k0, K, Blds, tid);
    __syncthreads();
#pragma unroll
    for (int kc = 0; kc < 2; ++kc) {
      bf16x8 af[4], bfr[4];
#pragma unroll
      for (int mi = 0; mi < 4; ++mi)
        af[mi] = frag_ld(Alds, wm * 64 + mi * 16 + l15, kc * 4 + quad);
#pragma unroll
      for (int ni = 0; ni < 4; ++ni)
        bfr[ni] = frag_ld(Blds, wn * 64 + ni * 16 + l15, kc * 4 + quad);
#pragma unroll
      for (int mi = 0; mi < 4; ++mi)
#pragma unroll
        for (int ni = 0; ni < 4; ++ni)
          acc[mi][ni] = __builtin_amdgcn_mfma_f32_16x16x32_bf16(
              af[mi], bfr[ni], acc[mi][ni], 0, 0, 0);
    }
    __syncthreads();
  }

#pragma unroll
  for (int mi = 0; mi < 4; ++mi) {
#pragma unroll
    for (int i = 0; i < 4; ++i) {
      int grow = m0 + wm * 64 + mi * 16 + quad * 4 + i;
#pragma unroll
      for (int ni = 0; ni < 4; ++ni) {
        int gcol = n0 + wn * 64 + ni * 16 + l15;
        out[grow * 1024 + gcol] = acc[mi][ni][i] + bias[gcol];
      }
    }
  }
}

// XCD-aware remap: lid&7 = XCD; each XCD owns 8 consecutive m-rows x all n.
__device__ __forceinline__ void remap_xcd(int lid, int& mblk, int& nblk) {
  int xcd = lid & 7;
  int j = lid >> 3;  // 0..63
  mblk = xcd * 8 + (j >> 3);
  nblk = j & 7;
}

__global__ __launch_bounds__(256) void gemm_out(const __bf16* __restrict__ A,
                                                const __bf16* __restrict__ B,
                                                const float* __restrict__ bias,
                                                float* __restrict__ out) {
  __shared__ alignas(16) __bf16 Alds[128 * 64];
  __shared__ alignas(16) __bf16 Blds[128 * 64];
  int mblk, nblk;
  remap_xcd(blockIdx.x, mblk, nblk);
  gemm_body(A, B, bias, out, 1024, mblk * 128, nblk * 128, Alds, Blds);
}

// Flash attention, register-resident P, all-MFMA at K=32 full rate.
// 1024 blocks (XCD-swizzled), 4 waves x 32 q-rows = 128 q/block, KV-64 dbuf.
// 32 KB LDS -> 4 blocks/CU -> 16 waves/CU = 4 waves/SIMD.
__global__ __launch_bounds__(256, 4) void attn_kernel(
    const __bf16* __restrict__ Qg, const __bf16* __restrict__ Kg,
    const __bf16* __restrict__ Vt, __bf16* __restrict__ AO) {
  __shared__ alignas(16) __bf16 Klds[2][64 * 64];  // also Q staging arena
  __shared__ alignas(16) __bf16 Vlds[2][64 * 64];

  const int tid = threadIdx.x;
  const int lane = tid & 63;
  const int w = tid >> 6;  // 0..3
  const int l15 = lane & 15, quad = lane >> 4;
  const int S = 2048;

  const int bid = blockIdx.x;
  const int r = bid >> 3;  // 0..127
  const int bh = (bid & 7) * 8 + (r & 7);
  const int q0 = (r >> 3) * 128;

  const __bf16* Qbase = Qg + (size_t)bh * S * 64;
  const __bf16* Kbase = Kg + (size_t)bh * S * 64;
  const __bf16* Vbase = Vt + (size_t)bh * 64 * S;

  // Stage Q (128x64 = 16 KB) into the K arena; move to registers.
  stage_tile<128, 256>(Qbase + q0 * 64, 64, (__bf16*)Klds, tid);
  __syncthreads();
  bf16x8 qf[2][2];  // [qi][kc]; q = w*32 + qi*16 + l15
#pragma unroll
  for (int qi = 0; qi < 2; ++qi)
#pragma unroll
    for (int kc = 0; kc < 2; ++kc)
      qf[qi][kc] =
          frag_ld((__bf16*)Klds, w * 32 + qi * 16 + l15, kc * 4 + quad);
  __syncthreads();  // arena now reusable for KV

  // Stage KV macro-tile 0.
  stage_tile<64, 256>(Kbase, 64, Klds[0], tid);
  stage_tile<64, 256>(Vbase, S, Vlds[0], tid);
  __syncthreads();

  const u32x4 ones_u = {0x3F803F80u, 0x3F803F80u, 0x3F803F80u, 0x3F803F80u};
  const bf16x8 ones8 = __builtin_bit_cast(bf16x8, ones_u);  // bf16 1.0 x8

  f32x4 oacc[2][4] = {};  // [qi][ni]
  f32x4 lacc[2] = {};     // [qi]; l at q = qi*16 + quad*4 + i

  for (int mt = 0; mt < 32; ++mt) {
    const int cur = mt & 1;
    if (mt + 1 < 32) {  // prefetch next KV macro-tile into the other buffer
      stage_tile<64, 256>(Kbase + (mt + 1) * 64 * 64, 64, Klds[cur ^ 1], tid);
      stage_tile<64, 256>(Vbase + (mt + 1) * 64, S, Vlds[cur ^ 1], tid);
    }

    // S^T = K.Q^T: sacc[ci][qi]; c = ci*16 + quad*4 + i, q = qi*16 + l15.
    f32x4 sacc[4][2] = {};
#pragma unroll
    for (int kc = 0; kc < 2; ++kc) {
      bf16x8 kf[4];
#pragma unroll
      for (int ci = 0; ci < 4; ++ci)
        kf[ci] = frag_ld(Klds[cur], ci * 16 + l15, kc * 4 + quad);
      __builtin_amdgcn_s_setprio(1);
#pragma unroll
      for (int ci = 0; ci < 4; ++ci)
#pragma unroll
        for (int qi = 0; qi < 2; ++qi)
          sacc[ci][qi] = __builtin_amdgcn_mfma_f32_16x16x32_bf16(
              kf[ci], qf[qi][kc], sacc[ci][qi], 0, 0, 0);
      __builtin_amdgcn_s_setprio(0);
    }

    // P = exp2(S^T) -> repack to K=32 A-frags; O += P V; l += P 1.
#pragma unroll
    for (int t = 0; t < 2; ++t) {  // 32-c block: ci = 2t, 2t+1
      bf16x8 vf[4];
#pragma unroll
      for (int ni = 0; ni < 4; ++ni)
        vf[ni] = frag_ld(Vlds[cur], ni * 16 + l15, t * 4 + quad);
#pragma unroll
      for (int qi = 0; qi < 2; ++qi) {
        float ea[4], eb[4];
#pragma unroll
        for (int i = 0; i < 4; ++i) {
          ea[i] = __builtin_amdgcn_exp2f(sacc[2 * t][qi][i]);
          eb[i] = __builtin_amdgcn_exp2f(sacc[2 * t + 1][qi][i]);
        }
        unsigned a0 = pk_bf16(ea[0], ea[1]);
        unsigned a1 = pk_bf16(ea[2], ea[3]);
        unsigned b0 = pk_bf16(eb[0], eb[1]);
        unsigned b1 = pk_bf16(eb[2], eb[3]);
        asm("v_permlane32_swap_b32 %0, %1" : "+v"(a0), "+v"(b0));
        asm("v_permlane16_swap_b32 %0, %1" : "+v"(a0), "+v"(b0));  // a0=F0 b0=F2
        asm("v_permlane32_swap_b32 %0, %1" : "+v"(a1), "+v"(b1));
        asm("v_permlane16_swap_b32 %0, %1" : "+v"(a1), "+v"(b1));  // a1=F1 b1=F3
        u32x4 pw = {a0, a1, b0, b1};
        bf16x8 pf = __builtin_bit_cast(bf16x8, pw);
        __builtin_amdgcn_s_setprio(1);
        lacc[qi] = __builtin_amdgcn_mfma_f32_16x16x32_bf16(pf, ones8, lacc[qi],
                                                           0, 0, 0);
#pragma unroll
        for (int ni = 0; ni < 4; ++ni)
          oacc[qi][ni] = __builtin_amdgcn_mfma_f32_16x16x32_bf16(
              pf, vf[ni], oacc[qi][ni], 0, 0, 0);
        __builtin_amdgcn_s_setprio(0);
      }
    }
    __syncthreads();  // drains prefetch vmcnt + guards buffer swap
  }

  const int b = bh >> 4;
  const int hh = bh & 15;
#pragma unroll
  for (int qi = 0; qi < 2; ++qi) {
#pragma unroll
    for (int i = 0; i < 4; ++i) {
      int s = q0 + w * 32 + qi * 16 + quad * 4 + i;
      float inv_l = 1.f / lacc[qi][i];
#pragma unroll
      for (int ni = 0; ni < 4; ++ni) {
        int d = ni * 16 + l15;
        AO[((size_t)(b * 2048 + s)) * 1024 + hh * 64 + d] =
            (__bf16)(oacc[qi][ni][i] * inv_l);
      }
    }
  }
}

extern "C" void kernel_launch(void* const* d_in, const int* in_sizes, int n_in,
                              void* d_out, int out_size, void* d_ws,
                              size_t ws_size, hipStream_t stream) {
  const float* q_in = (const float*)d_in[0];
  const float* k_in = (const float*)d_in[1];
  const float* v_in = (const float*)d_in[2];
  const float* Wq = (const float*)d_in[3];
  const float* bq = (const float*)d_in[4];
  const float* Wk = (const float*)d_in[5];
  const float* bk = (const float*)d_in[6];
  const float* Wv = (const float*)d_in[7];
  const float* bv = (const float*)d_in[8];
  const float* Wo = (const float*)d_in[9];
  const float* bo = (const float*)d_in[10];

  const size_t SZ_X = (size_t)8192 * 1024 * 2;  // 16 MB bf16
  const size_t SZ_W = (size_t)1024 * 1024 * 2;  // 2 MB bf16
  char* p = (char*)d_ws;
  __bf16* xq = (__bf16*)p; p += SZ_X;
  __bf16* xk = (__bf16*)p; p += SZ_X;
  __bf16* xv = (__bf16*)p; p += SZ_X;
  __bf16* wqb = (__bf16*)p; p += SZ_W;
  __bf16* wkb = (__bf16*)p; p += SZ_W;
  __bf16* wvb = (__bf16*)p; p += SZ_W;
  __bf16* wob = (__bf16*)p; p += SZ_W;
  __bf16* Qb = (__bf16*)p; p += SZ_X;   // [B,H,S,64] (scaled)
  __bf16* Kb = (__bf16*)p; p += SZ_X;   // [B,H,S,64]
  __bf16* Vtb = (__bf16*)p; p += SZ_X;  // [B,H,64,S]
  __bf16* AOb = (__bf16*)p; p += SZ_X;  // [B,S,1024]

  const int nx4 = 8192 * 1024 / 4, nw4 = 1024 * 1024 / 4;
  cvt_all<<<dim3(nx4 / 256, 7), 256, 0, stream>>>(
      q_in, k_in, v_in, Wq, Wk, Wv, Wo, xq, xk, xv, wqb, wkb, wvb, wob, nx4,
      nw4);

  gemm8_qkv<<<dim3(128, 3), 512, 0, stream>>>(xq, xk, xv, wqb, wkb, wvb, bq,
                                              bk, bv, Qb, Kb, Vtb);

  attn_kernel<<<1024, 256, 0, stream>>>(Qb, Kb, Vtb, AOb);

  gemm_out<<<512, 256, 0, stream>>>(AOb, wob, bo, (float*)d_out);
}

// Round 7
// 325.927 us; speedup vs baseline: 1.0957x; 1.0957x over previous
//
#include <hip/hip_runtime.h>

// MHA: B=4, H=16, S=2048, D_MODEL=1024, DK=64. fp32 in/out, bf16 MFMA compute.
// R12 (3rd submit; R5/R6 benches were GPU-acquisition timeouts, never ran):
// revert to the R9 anchor (332us best) after two in-block-pipelining
// regressions (R10 dbuf 111us, R11 8-phase 131us): at K=1024 with a
// 1536-block grid, cross-block TLP (5 blocks/CU, single-buffer 128^2) beats
// in-block overlap. One new change: cvt_all was launching 57344 blocks with
// 28672 idle (z>=3 slices sized for the big tensors); now a flat grid-stride
// 2048-block kernel, 14 float4/thread exact, region decode by shifts
// (2^18-aligned boundaries -> wave-uniform branches). GEMMs and attn are
// byte-identical to R9.

typedef __attribute__((ext_vector_type(8))) __bf16 bf16x8;
typedef __attribute__((ext_vector_type(4))) __bf16 bf16x4;
typedef __attribute__((ext_vector_type(4))) float f32x4;
typedef __attribute__((ext_vector_type(4))) unsigned int u32x4;

#define SCALE_FOLD 0.18033688011112043f  // log2(e) / sqrt(64), folded into Q

__device__ __forceinline__ void async_copy16(const void* g, void* lds) {
  __builtin_amdgcn_global_load_lds(
      (const __attribute__((address_space(1))) void*)g,
      (__attribute__((address_space(3))) void*)lds, 16, 0, 0);
}

// Stage a [ROWS x 64 bf16] tile (row pitch `ld` elems) into LDS, 16B/lane,
// XOR chunk swizzle: LDS slot (row, c) holds global chunk c ^ (row & 7).
template <int ROWS, int THREADS>
__device__ __forceinline__ void stage_tile(const __bf16* __restrict__ g, int ld,
                                           __bf16* lds, int tid) {
  const int wave_base = tid & ~63;
#pragma unroll
  for (int r = 0; r < ROWS * 8 / THREADS; ++r) {
    int slot = r * THREADS + tid;
    int row = slot >> 3;
    int c = slot & 7;
    int gc = c ^ (row & 7);
    async_copy16(g + row * ld + gc * 8, lds + (r * THREADS + wave_base) * 8);
  }
}

// Read one 8-elem (16B) fragment chunk from a width-64 XOR-swizzled tile.
__device__ __forceinline__ bf16x8 frag_ld(const __bf16* lds, int row, int chunk) {
  return *(const bf16x8*)(lds + row * 64 + ((chunk ^ (row & 7)) << 3));
}

// Pack two fp32 into one u32 of 2 bf16 (lo, hi). Compiler fuses the casts.
__device__ __forceinline__ unsigned pk_bf16(float lo, float hi) {
  unsigned short l = __builtin_bit_cast(unsigned short, (__bf16)lo);
  unsigned short h = __builtin_bit_cast(unsigned short, (__bf16)hi);
  return (unsigned)l | ((unsigned)h << 16);
}

// Flat grid-stride fp32->bf16 for all 7 tensors. Layout (float4 units):
// [0, 3*2^21): big tensors (q,k,v: 2^21 each); then 4 weights (2^18 each).
// 2048 blocks x 256 threads x 14 iters = 7340032 float4 exactly.
__global__ __launch_bounds__(256) void cvt_all(
    const float* __restrict__ s0, const float* __restrict__ s1,
    const float* __restrict__ s2, const float* __restrict__ s3,
    const float* __restrict__ s4, const float* __restrict__ s5,
    const float* __restrict__ s6, __bf16* __restrict__ d0,
    __bf16* __restrict__ d1, __bf16* __restrict__ d2, __bf16* __restrict__ d3,
    __bf16* __restrict__ d4, __bf16* __restrict__ d5,
    __bf16* __restrict__ d6) {
  int idx = blockIdx.x * 256 + threadIdx.x;
  for (int it = 0; it < 14; ++it, idx += 2048 * 256) {
    const float* src;
    __bf16* dst;
    int off;
    if (idx < (3 << 21)) {
      int t = idx >> 21;
      off = idx & ((1 << 21) - 1);
      src = t == 0 ? s0 : (t == 1 ? s1 : s2);
      dst = t == 0 ? d0 : (t == 1 ? d1 : d2);
    } else {
      int j = idx - (3 << 21);
      int t = j >> 18;
      off = j & ((1 << 18) - 1);
      src = t == 0 ? s3 : (t == 1 ? s4 : (t == 2 ? s5 : s6));
      dst = t == 0 ? d3 : (t == 1 ? d4 : (t == 2 ? d5 : d6));
    }
    float4 v = ((const float4*)src)[off];
    bf16x4 o = {(__bf16)v.x, (__bf16)v.y, (__bf16)v.z, (__bf16)v.w};
    ((bf16x4*)dst)[off] = o;
  }
}

// Shared NT-GEMM body: C[m,n] = sum_k A[m,k]*B[n,k] (+bias), 128x128 tile,
// BK=64, 4 waves 2x2, 4x4 MFMA 16x16x32 per wave. (R9 structure: single
// buffer, 32KB LDS -> 5 blocks/CU; cross-block TLP hides staging.)
__device__ __forceinline__ void gemm_body(const __bf16* __restrict__ A,
                                          const __bf16* __restrict__ B,
                                          const float* __restrict__ bias,
                                          void* __restrict__ out, int K,
                                          int mode, int m0, int n0,
                                          __bf16* Alds, __bf16* Blds) {
  const int tid = threadIdx.x;
  const int lane = tid & 63;
  const int w = tid >> 6;
  const int wm = w >> 1, wn = w & 1;
  const int l15 = lane & 15, quad = lane >> 4;

  f32x4 acc[4][4] = {};

  for (int k0 = 0; k0 < K; k0 += 64) {
    stage_tile<128, 256>(A + m0 * K + k0, K, Alds, tid);
    stage_tile<128, 256>(B + n0 * K + k0, K, Blds, tid);
    __syncthreads();
#pragma unroll
    for (int kc = 0; kc < 2; ++kc) {
      bf16x8 af[4], bfr[4];
#pragma unroll
      for (int mi = 0; mi < 4; ++mi)
        af[mi] = frag_ld(Alds, wm * 64 + mi * 16 + l15, kc * 4 + quad);
#pragma unroll
      for (int ni = 0; ni < 4; ++ni)
        bfr[ni] = frag_ld(Blds, wn * 64 + ni * 16 + l15, kc * 4 + quad);
#pragma unroll
      for (int mi = 0; mi < 4; ++mi)
#pragma unroll
        for (int ni = 0; ni < 4; ++ni)
          acc[mi][ni] = __builtin_amdgcn_mfma_f32_16x16x32_bf16(
              af[mi], bfr[ni], acc[mi][ni], 0, 0, 0);
    }
    __syncthreads();
  }

#pragma unroll
  for (int mi = 0; mi < 4; ++mi) {
#pragma unroll
    for (int i = 0; i < 4; ++i) {
      int grow = m0 + wm * 64 + mi * 16 + quad * 4 + i;
#pragma unroll
      for (int ni = 0; ni < 4; ++ni) {
        int gcol = n0 + wn * 64 + ni * 16 + l15;
        float v = acc[mi][ni][i];
        if (mode == 3) {
          v += bias[gcol];
          ((float*)out)[grow * 1024 + gcol] = v;
        } else if (mode == 2) {
          v += bias[grow];
          int h = grow >> 6, dd = grow & 63;
          int b = gcol >> 11, s = gcol & 2047;
          ((__bf16*)out)[(((b * 16 + h) * 64 + dd) * 2048) + s] = (__bf16)v;
        } else {
          v += bias[gcol];
          if (mode == 0) v *= SCALE_FOLD;
          int h = gcol >> 6, dd = gcol & 63;
          int b = grow >> 11, s = grow & 2047;
          ((__bf16*)out)[(((b * 16 + h) * 2048 + s) * 64) + dd] = (__bf16)v;
        }
      }
    }
  }
}

// XCD-aware remap: lid&7 = XCD; each XCD owns 8 consecutive m-rows x all n.
__device__ __forceinline__ void remap_xcd(int lid, int& mblk, int& nblk) {
  int xcd = lid & 7;
  int j = lid >> 3;  // 0..63
  mblk = xcd * 8 + (j >> 3);
  nblk = j & 7;
}

__global__ __launch_bounds__(256) void gemm_qkv(
    const __bf16* __restrict__ xq, const __bf16* __restrict__ xk,
    const __bf16* __restrict__ xv, const __bf16* __restrict__ wq,
    const __bf16* __restrict__ wk, const __bf16* __restrict__ wv,
    const float* __restrict__ bq, const float* __restrict__ bk,
    const float* __restrict__ bv, __bf16* Qb, __bf16* Kb, __bf16* Vtb) {
  __shared__ alignas(16) __bf16 Alds[128 * 64];
  __shared__ alignas(16) __bf16 Blds[128 * 64];
  int mblk, nblk;
  remap_xcd(blockIdx.x, mblk, nblk);
  const int z = blockIdx.y;
  if (z == 0) {
    gemm_body(xq, wq, bq, Qb, 1024, 0, mblk * 128, nblk * 128, Alds, Blds);
  } else if (z == 1) {
    gemm_body(xk, wk, bk, Kb, 1024, 1, mblk * 128, nblk * 128, Alds, Blds);
  } else {
    // V operand-swapped: A = Wv (M=1024), B = xv (N=8192) -> coalesced V^T.
    gemm_body(wv, xv, bv, Vtb, 1024, 2, nblk * 128, mblk * 128, Alds, Blds);
  }
}

__global__ __launch_bounds__(256) void gemm_out(const __bf16* __restrict__ A,
                                                const __bf16* __restrict__ B,
                                                const float* __restrict__ bias,
                                                float* __restrict__ out) {
  __shared__ alignas(16) __bf16 Alds[128 * 64];
  __shared__ alignas(16) __bf16 Blds[128 * 64];
  int mblk, nblk;
  remap_xcd(blockIdx.x, mblk, nblk);
  gemm_body(A, B, bias, out, 1024, 3, mblk * 128, nblk * 128, Alds, Blds);
}

// Flash attention, register-resident P, all-MFMA at K=32 full rate.
// 1024 blocks (XCD-swizzled), 4 waves x 32 q-rows = 128 q/block, KV-64 dbuf.
// 32 KB LDS -> 4 blocks/CU -> 16 waves/CU = 4 waves/SIMD.
// S^T = K.Q^T via 16x16x32: sacc[ci][qi], c = ci*16 + quad*4 + i, q = qi*16
// + l15 (q local to wave: w*32 + ...). P = exp2(S^T) repacked in-register to
// the 16x16x32 A-layout (k = quad*8 + j) via cvt-pack + v_permlane32_swap +
// v_permlane16_swap:
//   per 32-c block t: A0,A1 = packed pairs from sacc[2t]; B0,B1 from
//   sacc[2t+1]. permlane32_swap(A0,B0) then permlane16_swap -> F0 (k=8q+0,1)
//   and F2 (k=8q+4,5); (A1,B1) -> F1, F3. Frag = {F0,F1,F2,F3}.
// PV and l via 16x16x32. l lands q = quad*4 + i (epilogue-indexed).
__global__ __launch_bounds__(256, 4) void attn_kernel(
    const __bf16* __restrict__ Qg, const __bf16* __restrict__ Kg,
    const __bf16* __restrict__ Vt, __bf16* __restrict__ AO) {
  __shared__ alignas(16) __bf16 Klds[2][64 * 64];  // also Q staging arena
  __shared__ alignas(16) __bf16 Vlds[2][64 * 64];

  const int tid = threadIdx.x;
  const int lane = tid & 63;
  const int w = tid >> 6;  // 0..3
  const int l15 = lane & 15, quad = lane >> 4;
  const int S = 2048;

  const int bid = blockIdx.x;
  const int r = bid >> 3;  // 0..127
  const int bh = (bid & 7) * 8 + (r & 7);
  const int q0 = (r >> 3) * 128;

  const __bf16* Qbase = Qg + (size_t)bh * S * 64;
  const __bf16* Kbase = Kg + (size_t)bh * S * 64;
  const __bf16* Vbase = Vt + (size_t)bh * 64 * S;

  // Stage Q (128x64 = 16 KB) into the K arena; move to registers.
  stage_tile<128, 256>(Qbase + q0 * 64, 64, (__bf16*)Klds, tid);
  __syncthreads();
  bf16x8 qf[2][2];  // [qi][kc]; q = w*32 + qi*16 + l15
#pragma unroll
  for (int qi = 0; qi < 2; ++qi)
#pragma unroll
    for (int kc = 0; kc < 2; ++kc)
      qf[qi][kc] =
          frag_ld((__bf16*)Klds, w * 32 + qi * 16 + l15, kc * 4 + quad);
  __syncthreads();  // arena now reusable for KV

  // Stage KV macro-tile 0.
  stage_tile<64, 256>(Kbase, 64, Klds[0], tid);
  stage_tile<64, 256>(Vbase, S, Vlds[0], tid);
  __syncthreads();

  const u32x4 ones_u = {0x3F803F80u, 0x3F803F80u, 0x3F803F80u, 0x3F803F80u};
  const bf16x8 ones8 = __builtin_bit_cast(bf16x8, ones_u);  // bf16 1.0 x8

  f32x4 oacc[2][4] = {};  // [qi][ni]
  f32x4 lacc[2] = {};     // [qi]; l at q = qi*16 + quad*4 + i

  for (int mt = 0; mt < 32; ++mt) {
    const int cur = mt & 1;
    if (mt + 1 < 32) {  // prefetch next KV macro-tile into the other buffer
      stage_tile<64, 256>(Kbase + (mt + 1) * 64 * 64, 64, Klds[cur ^ 1], tid);
      stage_tile<64, 256>(Vbase + (mt + 1) * 64, S, Vlds[cur ^ 1], tid);
    }

    // S^T = K.Q^T: sacc[ci][qi]; c = ci*16 + quad*4 + i, q = qi*16 + l15.
    f32x4 sacc[4][2] = {};
#pragma unroll
    for (int kc = 0; kc < 2; ++kc) {
      bf16x8 kf[4];
#pragma unroll
      for (int ci = 0; ci < 4; ++ci)
        kf[ci] = frag_ld(Klds[cur], ci * 16 + l15, kc * 4 + quad);
      __builtin_amdgcn_s_setprio(1);
#pragma unroll
      for (int ci = 0; ci < 4; ++ci)
#pragma unroll
        for (int qi = 0; qi < 2; ++qi)
          sacc[ci][qi] = __builtin_amdgcn_mfma_f32_16x16x32_bf16(
              kf[ci], qf[qi][kc], sacc[ci][qi], 0, 0, 0);
      __builtin_amdgcn_s_setprio(0);
    }

    // P = exp2(S^T) -> repack to K=32 A-frags; O += P V; l += P 1.
#pragma unroll
    for (int t = 0; t < 2; ++t) {  // 32-c block: ci = 2t, 2t+1
      bf16x8 vf[4];
#pragma unroll
      for (int ni = 0; ni < 4; ++ni)
        vf[ni] = frag_ld(Vlds[cur], ni * 16 + l15, t * 4 + quad);
#pragma unroll
      for (int qi = 0; qi < 2; ++qi) {
        float ea[4], eb[4];
#pragma unroll
        for (int i = 0; i < 4; ++i) {
          ea[i] = __builtin_amdgcn_exp2f(sacc[2 * t][qi][i]);
          eb[i] = __builtin_amdgcn_exp2f(sacc[2 * t + 1][qi][i]);
        }
        unsigned a0 = pk_bf16(ea[0], ea[1]);
        unsigned a1 = pk_bf16(ea[2], ea[3]);
        unsigned b0 = pk_bf16(eb[0], eb[1]);
        unsigned b1 = pk_bf16(eb[2], eb[3]);
        asm("v_permlane32_swap_b32 %0, %1" : "+v"(a0), "+v"(b0));
        asm("v_permlane16_swap_b32 %0, %1" : "+v"(a0), "+v"(b0));  // a0=F0 b0=F2
        asm("v_permlane32_swap_b32 %0, %1" : "+v"(a1), "+v"(b1));
        asm("v_permlane16_swap_b32 %0, %1" : "+v"(a1), "+v"(b1));  // a1=F1 b1=F3
        u32x4 pw = {a0, a1, b0, b1};
        bf16x8 pf = __builtin_bit_cast(bf16x8, pw);
        __builtin_amdgcn_s_setprio(1);
        lacc[qi] = __builtin_amdgcn_mfma_f32_16x16x32_bf16(pf, ones8, lacc[qi],
                                                           0, 0, 0);
#pragma unroll
        for (int ni = 0; ni < 4; ++ni)
          oacc[qi][ni] = __builtin_amdgcn_mfma_f32_16x16x32_bf16(
              pf, vf[ni], oacc[qi][ni], 0, 0, 0);
        __builtin_amdgcn_s_setprio(0);
      }
    }
    __syncthreads();  // drains prefetch vmcnt + guards buffer swap
  }

  const int b = bh >> 4;
  const int hh = bh & 15;
#pragma unroll
  for (int qi = 0; qi < 2; ++qi) {
#pragma unroll
    for (int i = 0; i < 4; ++i) {
      int s = q0 + w * 32 + qi * 16 + quad * 4 + i;
      float inv_l = 1.f / lacc[qi][i];
#pragma unroll
      for (int ni = 0; ni < 4; ++ni) {
        int d = ni * 16 + l15;
        AO[((size_t)(b * 2048 + s)) * 1024 + hh * 64 + d] =
            (__bf16)(oacc[qi][ni][i] * inv_l);
      }
    }
  }
}

extern "C" void kernel_launch(void* const* d_in, const int* in_sizes, int n_in,
                              void* d_out, int out_size, void* d_ws,
                              size_t ws_size, hipStream_t stream) {
  const float* q_in = (const float*)d_in[0];
  const float* k_in = (const float*)d_in[1];
  const float* v_in = (const float*)d_in[2];
  const float* Wq = (const float*)d_in[3];
  const float* bq = (const float*)d_in[4];
  const float* Wk = (const float*)d_in[5];
  const float* bk = (const float*)d_in[6];
  const float* Wv = (const float*)d_in[7];
  const float* bv = (const float*)d_in[8];
  const float* Wo = (const float*)d_in[9];
  const float* bo = (const float*)d_in[10];

  const size_t SZ_X = (size_t)8192 * 1024 * 2;  // 16 MB bf16
  const size_t SZ_W = (size_t)1024 * 1024 * 2;  // 2 MB bf16
  char* p = (char*)d_ws;
  __bf16* xq = (__bf16*)p; p += SZ_X;
  __bf16* xk = (__bf16*)p; p += SZ_X;
  __bf16* xv = (__bf16*)p; p += SZ_X;
  __bf16* wqb = (__bf16*)p; p += SZ_W;
  __bf16* wkb = (__bf16*)p; p += SZ_W;
  __bf16* wvb = (__bf16*)p; p += SZ_W;
  __bf16* wob = (__bf16*)p; p += SZ_W;
  __bf16* Qb = (__bf16*)p; p += SZ_X;   // [B,H,S,64] (scaled)
  __bf16* Kb = (__bf16*)p; p += SZ_X;   // [B,H,S,64]
  __bf16* Vtb = (__bf16*)p; p += SZ_X;  // [B,H,64,S]
  __bf16* AOb = (__bf16*)p; p += SZ_X;  // [B,S,1024]

  cvt_all<<<2048, 256, 0, stream>>>(q_in, k_in, v_in, Wq, Wk, Wv, Wo, xq, xk,
                                    xv, wqb, wkb, wvb, wob);

  gemm_qkv<<<dim3(512, 3), 256, 0, stream>>>(xq, xk, xv, wqb, wkb, wvb, bq,
                                             bk, bv, Qb, Kb, Vtb);

  attn_kernel<<<1024, 256, 0, stream>>>(Qb, Kb, Vtb, AOb);

  gemm_out<<<512, 256, 0, stream>>>(AOb, wob, bo, (float*)d_out);
}